// Round 9
// baseline (71.605 us; speedup 1.0000x reference)
//
#include <hip/hip_runtime.h>

// Tropical (max-plus) linear layer:
//   out[b, j] = max_k (x[b,k] + w[j,k]) + bias[j]   if any product > -1e38
//             = -1e38                                otherwise
// x: [4096, 256] f32, w: [256, 256] f32, bias: [256] f32, out: [4096, 256] f32
//
// R12 = R11 arithmetic, 2x TLP (the one untried lever).
//  - Ledger: VALU -31% null, memory-path x4 null, w-coalescing null,
//    dispatch -1 real, => kernel (11.8us marginal, R10-measured) is
//    LATENCY-bound, and every round so far ran only 4 waves/SIMD.
//  - R12: 1 col/lane (COLS=64). w fragment = 8 float4 = 32 VGPRs (was 64),
//    x stays in SGPRs -> ~50-60 VGPR => launch_bounds(512,8) fits the
//    <=64-VGPR occupancy step. LDS part[8][16][64]=32KB -> 4 blocks/CU
//    -> 32 waves/CU = 8/SIMD, double R11's latency cover. 8192 waves,
//    same ~4.6M total wave-instrs, half the per-wave critical path.
//  - Pre-committed: ~67-69us => TLP mechanism confirmed; >=70.5 => all
//    mechanism classes nulled, declare ROOFLINE next round.

#define TZERO -1e38f

constexpr int K    = 256;
constexpr int N    = 256;
constexpr int ROWS = 16;    // rows per block
constexpr int COLS = 64;    // cols per block (1 per lane)
constexpr int NT   = 512;   // 8 waves = 8 k-segments
constexpr int KSEG = 32;    // k-extent per wave

typedef float f32x2 __attribute__((ext_vector_type(2)));

// packed add: d = {xs.x + wv.x, xs.y + wv.y}; xs is wave-uniform (SGPR pair)
__device__ __forceinline__ f32x2 pk_add_sv(f32x2 xs, f32x2 wv)
{
    f32x2 r;
    asm("v_pk_add_f32 %0, %1, %2" : "=v"(r) : "s"(xs), "v"(wv));
    return r;
}

// one column per lane: 8 x (2 pk_add + 2 v_max3) = 32 VALU per row
__device__ __forceinline__ void row_compute(
    const float4 (&buf)[8], const float4 (&wA)[8], float& a)
{
    float p0 = -__builtin_inff(), p1 = -__builtin_inff();
#pragma unroll
    for (int i = 0; i < 8; ++i) {
        const f32x2 xlo = {buf[i].x, buf[i].y};   // SGPR pair, even-aligned
        const f32x2 xhi = {buf[i].z, buf[i].w};   // SGPR pair, even-aligned
        const f32x2 wa0 = {wA[i].x, wA[i].y};     // VGPR quad subpairs
        const f32x2 wa1 = {wA[i].z, wA[i].w};
        const f32x2 r0 = pk_add_sv(xlo, wa0);
        const f32x2 r1 = pk_add_sv(xhi, wa1);
        p0 = fmaxf(fmaxf(p0, r0.x), r0.y);        // v_max3_f32
        p1 = fmaxf(fmaxf(p1, r1.x), r1.y);        // v_max3_f32
    }
    a = fmaxf(p0, p1);
}

__global__ __launch_bounds__(NT, 8)   // cap VGPR at 64 -> 8 waves/SIMD
void tropical_kernel(const float* __restrict__ x, const float* __restrict__ w,
                     const float* __restrict__ bias, float* __restrict__ out)
{
    __shared__ float part[8][ROWS][COLS];   // 32 KB -> 4 blocks/CU

    const int t    = threadIdx.x;
    const int lane = t & 63;
    const int ws   = __builtin_amdgcn_readfirstlane(t >> 6);  // k-segment id
    const int row0 = blockIdx.x * ROWS;
    const int col0 = blockIdx.y * COLS;

    // ---- w fragment: 1 col x 32 k, contiguous per lane (128 B), 8 float4
    //      = 32 VGPRs. Lanes stride 1KB (measured equal to coalesced, R7).
    const int k0 = ws * KSEG;
    const float* wp = w + (size_t)(col0 + lane) * K + k0;
    float4 wA[8];
#pragma unroll
    for (int i = 0; i < 8; ++i)
        wA[i] = *reinterpret_cast<const float4*>(wp + 4 * i);

    // ---- x through the scalar path: 8 float4 = 32 SGPRs per row buffer,
    //      2-row double-buffer with NAMED static buffers (no runtime index)
    const float* xp = x + (size_t)row0 * K + k0;   // wave-uniform base

    float4 bA[8], bB[8];
#pragma unroll
    for (int i = 0; i < 8; ++i)
        bA[i] = *reinterpret_cast<const float4*>(xp + 4 * i);   // row 0

    float a;
#pragma unroll 1
    for (int r = 0; r < ROWS; r += 2) {
        // prefetch row r+1 while computing row r
#pragma unroll
        for (int i = 0; i < 8; ++i)
            bB[i] = *reinterpret_cast<const float4*>(xp + (r + 1) * K + 4 * i);

        row_compute(bA, wA, a);
        part[ws][r][lane] = a;

        if (r + 2 < ROWS) {
#pragma unroll
            for (int i = 0; i < 8; ++i)
                bA[i] = *reinterpret_cast<const float4*>(xp + (r + 2) * K + 4 * i);
        }

        row_compute(bB, wA, a);
        part[ws][r + 1][lane] = a;
    }

    __syncthreads();

    // ---- epilogue: 8-way k-segment combine, bias, guard, coalesced store
    //      16 rows x 64 cols = 1024 outputs, 2 per thread
    {
        const int c  = t & 63;
        const int rb = t >> 6;             // 0..7
        const float bj = bias[col0 + c];
#pragma unroll
        for (int j = 0; j < 2; ++j) {
            const int r = rb + 8 * j;
            float v = part[0][r][c];
#pragma unroll
            for (int s = 1; s < 8; ++s) v = fmaxf(v, part[s][r][c]);
            out[(size_t)(row0 + r) * N + col0 + c] = (v > TZERO) ? v + bj : TZERO;
        }
    }
}

extern "C" void kernel_launch(void* const* d_in, const int* in_sizes, int n_in,
                              void* d_out, int out_size, void* d_ws, size_t ws_size,
                              hipStream_t stream) {
    const float* x  = (const float*)d_in[0];
    const float* w  = (const float*)d_in[1];
    const float* b  = (const float*)d_in[2];
    float* out      = (float*)d_out;

    dim3 grid(4096 / ROWS, N / COLS);    // (256, 4) = 1024 blocks, 8 waves each
    tropical_kernel<<<grid, NT, 0, stream>>>(x, w, b, out);
}